// Round 11
// baseline (192.226 us; speedup 1.0000x reference)
//
#include <hip/hip_runtime.h>
#include <hip/hip_bf16.h>

typedef unsigned short u16;
typedef __attribute__((ext_vector_type(8))) short bf16x8;
typedef __attribute__((ext_vector_type(4))) float f32x4;
typedef __attribute__((ext_vector_type(16))) float f32x16;
typedef __attribute__((ext_vector_type(4))) unsigned short u16x4;
typedef __attribute__((ext_vector_type(8))) unsigned short u16x8;

#define BATCH 4096
#define INF   1024
#define NH    4096   // 64 leaves * 64 hidden
#define OUTF  512
#define NLEAF 64
#define FDEPTH 6
#define ZSPL  4      // GEMM2 split-K ways

// Scratch as device globals (fully rewritten every call; no ws_size dependency).
__device__ __align__(16) u16  g_Xb[(size_t)BATCH * INF];     // x, bf16 (b,k)
__device__ __align__(16) u16  g_W1t[(size_t)NH * INF];       // W1 transposed: (n,k)
__device__ __align__(16) u16  g_W2t[(size_t)OUTF * NH];      // W2 transposed: (o,k)
__device__ __align__(16) u16  g_NWh[(size_t)64 * INF];       // node weights bf16 (row63=0)
__device__ __align__(16) u16  g_B2t[(size_t)OUTF * 64];      // b2s transposed (o,l) bf16
__device__ __align__(16) u16  g_Hb[(size_t)BATCH * NH];      // H' = mix*relu(h), bf16
__device__ __align__(16) float g_mix[(size_t)BATCH * NLEAF];
__device__ __align__(16) float g_part[(size_t)ZSPL * BATCH * OUTF];  // GEMM2 partials

__device__ inline u16 f2b(float f) {
  __hip_bfloat16 h = __float2bfloat16(f);
  return *reinterpret_cast<u16*>(&h);
}

// Direct global->LDS DMA, 16 B per lane; LDS dest = wave-uniform base + lane*16.
__device__ inline void async16(const u16* g, u16* l) {
  __builtin_amdgcn_global_load_lds((const __attribute__((address_space(1))) void*)g,
                                   (__attribute__((address_space(3))) void*)l, 16, 0, 0);
}

// ------------- merged prep: casts + transposes, section-decoded -------------
__global__ __launch_bounds__(256) void prep_kernel(
    const float* __restrict__ x, const float* __restrict__ nw,
    const float* __restrict__ w1s, const float* __restrict__ w2s,
    const float* __restrict__ b2s) {
  __shared__ float tile[64 * 65];
  const int b = blockIdx.x;
  const int t = threadIdx.x;

  if (b < 2048) {  // ---- cast x ----
    int i = (b * 256 + t) * 8;
    float4 v0 = *(const float4*)(x + i);
    float4 v1 = *(const float4*)(x + i + 4);
    u16x8 h;
    h[0] = f2b(v0.x); h[1] = f2b(v0.y); h[2] = f2b(v0.z); h[3] = f2b(v0.w);
    h[4] = f2b(v1.x); h[5] = f2b(v1.y); h[6] = f2b(v1.z); h[7] = f2b(v1.w);
    *(u16x8*)(g_Xb + i) = h;
    return;
  }
  if (b < 2112) {  // ---- cast nw ----
    int idx = ((b - 2048) * 256 + t) * 4;
    int n = idx >> 10;
    float4 v = make_float4(0.f, 0.f, 0.f, 0.f);
    if (n < 63) v = *(const float4*)(nw + idx);
    u16x4 h;
    h[0] = f2b(v.x); h[1] = f2b(v.y); h[2] = f2b(v.z); h[3] = f2b(v.w);
    *(u16x4*)(g_NWh + idx) = h;
    return;
  }

  // ---- transpose-cast sections: dst[c][r] = src[r][c] per 64x64 tile ----
  const float* sb;
  u16* db;
  int R, C, r0, c0;
  if (b < 3136) {
    int idx = b - 2112;
    int z = idx >> 4;
    R = 1024; C = 64;
    r0 = (idx & 15) * 64; c0 = 0;
    sb = w1s + (size_t)z * R * C;
    db = g_W1t + (size_t)z * R * C;
  } else if (b < 3648) {
    int idx = b - 3136;
    R = 4096; C = 512;
    r0 = (idx >> 3) * 64; c0 = (idx & 7) * 64;
    sb = w2s;
    db = g_W2t;
  } else {
    int idx = b - 3648;
    R = 64; C = 512;
    r0 = 0; c0 = idx * 64;
    sb = b2s;
    db = g_B2t;
  }
  int cc4 = (t & 15) * 4;
#pragma unroll
  for (int it = 0; it < 4; ++it) {
    int rr = (t >> 4) + it * 16;
    float4 v = *(const float4*)(sb + (size_t)(r0 + rr) * C + c0 + cc4);
    tile[rr * 65 + cc4 + 0] = v.x;
    tile[rr * 65 + cc4 + 1] = v.y;
    tile[rr * 65 + cc4 + 2] = v.z;
    tile[rr * 65 + cc4 + 3] = v.w;
  }
  __syncthreads();
  int cc = t >> 2, rch = (t & 3) * 16;
  u16x8 o0, o1;
#pragma unroll
  for (int j = 0; j < 8; ++j) o0[j] = f2b(tile[(rch + j) * 65 + cc]);
#pragma unroll
  for (int j = 0; j < 8; ++j) o1[j] = f2b(tile[(rch + 8 + j) * 65 + cc]);
  u16* p = db + (size_t)(c0 + cc) * R + r0 + rch;
  *(u16x8*)p = o0;
  *(u16x8*)(p + 8) = o1;
}

// ------------- fused mixture: MFMA logits + sigmoid + tree product -> g_mix
//               + MFMA seed out = mix@b2 -------------
__global__ __launch_bounds__(256) void mixture_kernel(
    const float* __restrict__ nb, float* __restrict__ out) {
  __shared__ __align__(16) unsigned char lds[57344];
  const int t = threadIdx.x;
  const int wv = t >> 6, ln = t & 63;
  const int quad = ln >> 4, m16 = ln & 15;
  const int r0 = blockIdx.x * 16;

  u16* stW = (u16*)(lds + wv * 10240);
  u16* stX = (u16*)(lds + wv * 10240 + 8192);
  float* lred = (float*)lds;
  float* ssig = (float*)(lds + 16384);
  u16* smixb = (u16*)(lds + 20480);
  u16* b2l = (u16*)(lds + 24576);

  f32x4 acc[4] = {};
#pragma unroll 1
  for (int it = 0; it < 4; ++it) {
    int kc = wv * 256 + it * 64;
#pragma unroll
    for (int j = 0; j < 8; ++j) {
      int id = j * 64 + ln;
      int row = id >> 3, c8 = (id & 7) ^ (row & 7);
      async16(g_NWh + (size_t)row * INF + kc + c8 * 8, stW + j * 512);
    }
#pragma unroll
    for (int j = 0; j < 2; ++j) {
      int id = j * 64 + ln;
      int row = id >> 3, c8 = (id & 7) ^ (row & 7);
      async16(g_Xb + (size_t)(r0 + row) * INF + kc + c8 * 8, stX + j * 512);
    }
    __syncthreads();
#pragma unroll
    for (int ks = 0; ks < 2; ++ks) {
      bf16x8 bF = *(const bf16x8*)(stX + m16 * 64 + ((ks * 4 + quad) ^ (m16 & 7)) * 8);
#pragma unroll
      for (int tw = 0; tw < 4; ++tw) {
        int row = tw * 16 + m16;
        bf16x8 aF = *(const bf16x8*)(stW + row * 64 + ((ks * 4 + quad) ^ (row & 7)) * 8);
        acc[tw] = __builtin_amdgcn_mfma_f32_16x16x32_bf16(aF, bF, acc[tw], 0, 0, 0);
      }
    }
    __syncthreads();
  }
#pragma unroll
  for (int tw = 0; tw < 4; ++tw)
#pragma unroll
    for (int r = 0; r < 4; ++r)
      lred[((size_t)wv * 64 + tw * 16 + quad * 4 + r) * 16 + m16] = acc[tw][r];
  __syncthreads();

#pragma unroll
  for (int j = 0; j < 8; ++j) {
    int id = (wv * 8 + j) * 64 + ln;
    int row = id >> 3, c8 = (id & 7) ^ (row & 7);
    async16(g_B2t + (size_t)row * 64 + c8 * 8, b2l + (wv * 8 + j) * 512);
  }

  {
    int n = t & 63, rg = t >> 6;
#pragma unroll
    for (int rr = 0; rr < 4; ++rr) {
      int row = rg * 4 + rr;
      float s = lred[(0 * 64 + n) * 16 + row] + lred[(1 * 64 + n) * 16 + row] +
                lred[(2 * 64 + n) * 16 + row] + lred[(3 * 64 + n) * 16 + row];
      if (n < 63) s += nb[n];
      ssig[row * 64 + n] = 1.f / (1.f + __expf(-s));
    }
  }
  __syncthreads();
  {
    int leaf = t & 63, rg = t >> 6;
#pragma unroll
    for (int rr = 0; rr < 4; ++rr) {
      int row = rg * 4 + rr;
      float p = 1.f;
#pragma unroll
      for (int d = 0; d < FDEPTH; ++d) {
        int node = (1 << d) - 1 + (leaf >> (FDEPTH - d));
        int bit = (leaf >> (FDEPTH - 1 - d)) & 1;
        float s = ssig[row * 64 + node];
        p *= bit ? s : (1.f - s);
      }
      g_mix[(size_t)(r0 + row) * 64 + leaf] = p;
      smixb[row * 64 + ((leaf >> 3) ^ (row & 7)) * 8 + (leaf & 7)] = f2b(p);
    }
  }
  __syncthreads();

  bf16x8 mixF[2];
#pragma unroll
  for (int ks = 0; ks < 2; ++ks)
    mixF[ks] = *(const bf16x8*)(smixb + m16 * 64 + ((ks * 4 + quad) ^ (m16 & 7)) * 8);
#pragma unroll 1
  for (int s = 0; s < 2; ++s) {
    f32x4 sacc[4] = {};
#pragma unroll
    for (int tile = 0; tile < 4; ++tile) {
#pragma unroll
      for (int ks = 0; ks < 2; ++ks) {
        int lrow = wv * 64 + tile * 16 + m16;
        bf16x8 aF = *(const bf16x8*)(b2l + lrow * 64 + ((ks * 4 + quad) ^ (lrow & 7)) * 8);
        sacc[tile] = __builtin_amdgcn_mfma_f32_16x16x32_bf16(aF, mixF[ks], sacc[tile], 0, 0, 0);
      }
    }
#pragma unroll
    for (int tile = 0; tile < 4; ++tile) {
      int o = s * 256 + wv * 64 + tile * 16 + quad * 4;
      *(f32x4*)(out + (size_t)(r0 + m16) * OUTF + o) = sacc[tile];
    }
    if (s == 0) {
      __syncthreads();
#pragma unroll
      for (int j = 0; j < 8; ++j) {
        int id = (wv * 8 + j) * 64 + ln;
        int row = id >> 3, c8 = (id & 7) ^ (row & 7);
        async16(g_B2t + (size_t)(256 + row) * 64 + c8 * 8, b2l + (wv * 8 + j) * 512);
      }
      __syncthreads();
    }
  }
}

// ------------- GEMM1: H'(b,n) = mix * relu(Xb @ W1t^T + b1) -------------
// R11: MERGED-PHASE schedule — 32 phases x 32 MFMA (was 64 x 16). Theory:
// R2 proved the phase floor (~1890 cy) is NOT throughput-bound (removing
// 190cy/phase of conflicts changed nothing); ~1200 cy/phase is fixed sync
// overhead (2 barriers x 8-wave convoy + drains). Merging the (AH=0,AH=1)
// pair into one phase keeps traffic/swizzle/tile IDENTICAL and halves the
// barrier count. Ring: 4 slots/operand, slot = chunk&3 (chunk = K/32).
// Phase p: read full slot p&3 (aF[8],bF[4], 12 ds_read_b128), stage chunk
// p+3 -> slot (p+3)&3 (4 DMAs), barrier, lgkmcnt(0), setprio, 32 MFMA,
// vmcnt(8) [= 2 newest stages in flight, chunk p+1 landed], barrier.
// Overwrite-safe: slot (p+3)&3 last read phase p-1, whose lgkmcnt(0)+
// barrier-2 precede phase p's stage issue. Prologue: chunks 0-2, vmcnt(8).
// Wrap stages (&31) are L2-hot dummies, drained by final vmcnt(0).
__global__ __launch_bounds__(512, 2) void gemm1_kernel(const float* __restrict__ b1) {
  __shared__ __align__(16) u16 s_lds[65536];  // 128 KiB
  u16* lsA = s_lds;            // 4 slots x 8192 u16 (256 rows x 32)
  u16* lsB = s_lds + 32768;

  const int t = threadIdx.x;
  const int wv = t >> 6, ln = t & 63;
  const int quad = ln >> 4, m16 = ln & 15;
  const int wm = wv >> 2, wn = wv & 3;      // 2 x 4 wave grid
  const int xcd = blockIdx.x & 7, slot = blockIdx.x >> 3;
  const int M0 = ((xcd >> 1) * 4 + (slot & 3)) * 256;   // weight rows (n)
  const int N0 = ((xcd & 1) * 8 + (slot >> 2)) * 256;   // batch rows (b)

  const int rhalf = ln >> 2;
  const int qg = (ln & 3) ^ ((ln >> 3) & 3);
  const u16* pA = g_W1t + (size_t)(M0 + wv * 32 + rhalf) * 1024 + qg * 8;
  const u16* pB = g_Xb + (size_t)(N0 + wv * 32 + rhalf) * 1024 + qg * 8;
  const int dst0 = wv * 1024;  // u16 offset of this wave's 2KB chunk in a slot

  // ds_read: row*32 + (quad ^ ((row>>1)&3))*8 ; (row>>1)&3 == (m16>>1)&3
  const int qx = (quad ^ ((m16 >> 1) & 3)) * 8;
  const int aro = (wm * 128 + m16) * 32 + qx;
  const int bro = (wn * 64 + m16) * 32 + qx;

  f32x4 acc[8][4] = {};

#define STAGE_A(SLOT, TCOL)                                \
  do {                                                     \
    const u16* gs = pA + (TCOL);                           \
    u16* dd = lsA + (SLOT) * 8192 + dst0;                  \
    async16(gs, dd);                                       \
    async16(gs + 16 * 1024, dd + 512);                     \
  } while (0)
#define STAGE_B(SLOT, TCOL)                                \
  do {                                                     \
    const u16* gs = pB + (TCOL);                           \
    u16* dd = lsB + (SLOT) * 8192 + dst0;                  \
    async16(gs, dd);                                       \
    async16(gs + 16 * 1024, dd + 512);                     \
  } while (0)

// Merged phase: SLOT = read slot (chunk p), SC = stage chunk (p+3).
#define G1_PHASE(SLOT, SC)                                                  \
  {                                                                         \
    const u16* Abase = lsA + (SLOT) * 8192;                                 \
    const u16* Bbase = lsB + (SLOT) * 8192;                                 \
    bf16x8 aF[8];                                                           \
    _Pragma("unroll") for (int f = 0; f < 8; ++f)                           \
        aF[f] = *(const bf16x8*)(Abase + aro + f * 512);                    \
    bf16x8 bF[4];                                                           \
    _Pragma("unroll") for (int g = 0; g < 4; ++g)                           \
        bF[g] = *(const bf16x8*)(Bbase + bro + g * 512);                    \
    STAGE_A((SC) & 3, ((SC) & 31) * 32);                                    \
    STAGE_B((SC) & 3, ((SC) & 31) * 32);                                    \
    __builtin_amdgcn_s_barrier();                                           \
    asm volatile("s_waitcnt lgkmcnt(0)" ::: "memory");                      \
    __builtin_amdgcn_s_setprio(1);                                          \
    _Pragma("unroll") for (int f = 0; f < 8; ++f)                           \
        _Pragma("unroll") for (int g = 0; g < 4; ++g)                       \
            acc[f][g] = __builtin_amdgcn_mfma_f32_16x16x32_bf16(            \
                aF[f], bF[g], acc[f][g], 0, 0, 0);                          \
    __builtin_amdgcn_s_setprio(0);                                          \
    asm volatile("s_waitcnt vmcnt(8)" ::: "memory");                        \
    __builtin_amdgcn_s_barrier();                                           \
  }

  // Prologue: chunks 0-2 (12 loads); vmcnt(8) -> chunk 0's 4 loads landed.
  STAGE_A(0, 0);
  STAGE_B(0, 0);
  STAGE_A(1, 32);
  STAGE_B(1, 32);
  STAGE_A(2, 64);
  STAGE_B(2, 64);
  asm volatile("s_waitcnt vmcnt(8)" ::: "memory");
  __builtin_amdgcn_s_barrier();

#pragma unroll 1
  for (int i = 0; i < 8; ++i) {  // 4 chunks (K=128) per iteration
    const int c = i * 4;
    G1_PHASE(0, c + 3);
    G1_PHASE(1, c + 4);
    G1_PHASE(2, c + 5);
    G1_PHASE(3, c + 6);
  }
#undef G1_PHASE
#undef STAGE_A
#undef STAGE_B

  asm volatile("s_waitcnt vmcnt(0)" ::: "memory");  // drain tail dummy DMAs

  // Epilogue: D col = batch (m16), D row = n (quad*4 + reg) — verified map.
  const int lb = (M0 >> 6) + wm * 2;  // leaf for fa<4; lb+1 for fa>=4
  float2 mx[4];
#pragma unroll
  for (int fb = 0; fb < 4; ++fb) {
    int bb = N0 + wn * 64 + fb * 16 + m16;
    mx[fb] = *(const float2*)(g_mix + (size_t)bb * 64 + lb);
  }
#pragma unroll
  for (int fa = 0; fa < 8; ++fa) {
    int n0 = M0 + wm * 128 + fa * 16 + quad * 4;
    float4 b1v = *(const float4*)(b1 + n0);
#pragma unroll
    for (int fb = 0; fb < 4; ++fb) {
      int bb = N0 + wn * 64 + fb * 16 + m16;
      float mixv = (fa < 4) ? mx[fb].x : mx[fb].y;
      u16x4 pk;
      pk[0] = f2b(fmaxf(acc[fa][fb][0] + b1v.x, 0.f) * mixv);
      pk[1] = f2b(fmaxf(acc[fa][fb][1] + b1v.y, 0.f) * mixv);
      pk[2] = f2b(fmaxf(acc[fa][fb][2] + b1v.z, 0.f) * mixv);
      pk[3] = f2b(fmaxf(acc[fa][fb][3] + b1v.w, 0.f) * mixv);
      *(u16x4*)(g_Hb + (size_t)bb * NH + n0) = pk;
    }
  }
}

// ------------- GEMM2: part[z](b,o) = Hb @ W2t^T (split-K partials) -------------
// R7 form (best measured total, 188.5 us). 8-phase port with 256 o x 128 b
// tile, ZSPL=4 -> 256 blocks x 512 thr, K=1024/block = 8 K-tiles. LDS: A
// 4x16KB + B 4x8KB = 96KB. vmcnt(4) = newest 3 stages (B1+A2+B1) in flight.
__global__ __launch_bounds__(512, 2) void gemm2_kernel() {
  __shared__ __align__(16) u16 s_lds[49152];  // 96 KiB
  u16* lsA = s_lds;            // W2t: 4 slots x 8192 u16 (256 rows x 32)
  u16* lsB = s_lds + 32768;    // Hb:  4 slots x 4096 u16 (128 rows x 32)

  const int t = threadIdx.x;
  const int wv = t >> 6, ln = t & 63;
  const int quad = ln >> 4, m16 = ln & 15;
  const int wm = wv >> 2, wn = wv & 3;      // wm: o-half (128), wn: b-quarter (32)
  const int xcd = blockIdx.x & 7, slot = blockIdx.x >> 3;   // 32 slots/XCD
  const int btile = xcd * 4 + (slot >> 3);  // 0..31 (128 batch rows each)
  const int rem = slot & 7;
  const int mtile = rem & 1, zidx = rem >> 1;
  const int N0 = btile * 128;               // batch base
  const int M0 = mtile * 256;               // o base
  const int kbeg = zidx * 1024;

  const int rhalf = ln >> 2;
  const int qg = (ln & 3) ^ ((ln >> 3) & 3);
  const u16* pA = g_W2t + (size_t)(M0 + wv * 32 + rhalf) * 4096 + kbeg + qg * 8;
  const u16* pB = g_Hb + (size_t)(N0 + wv * 16 + rhalf) * 4096 + kbeg + qg * 8;
  const int dstA = wv * 1024;  // wave's 2KB chunk in a 16KB A-slot
  const int dstB = wv * 512;   // wave's 1KB chunk in an 8KB B-slot

  const int qx = (quad ^ ((m16 >> 1) & 3)) * 8;
  const int aro = (wm * 128 + m16) * 32 + qx;
  const int bro = (wn * 32 + m16) * 32 + qx;

  f32x4 acc[8][2] = {};
  bf16x8 bF[2];

#define STAGE_A2(SLOT, TCOL)                               \
  do {                                                     \
    const u16* gs = pA + (TCOL);                           \
    u16* dd = lsA + (SLOT) * 8192 + dstA;                  \
    async16(gs, dd);                                       \
    async16(gs + 16 * 4096, dd + 512);                     \
  } while (0)
#define STAGE_B2(SLOT, TCOL)                               \
  do {                                                     \
    const u16* gs = pB + (TCOL);                           \
    u16* dd = lsB + (SLOT) * 4096 + dstB;                  \
    async16(gs, dd);                                       \
  } while (0)

#define G2_PHASE(ASLOT, BSLOT, AH, RELOAD_B, STAGE_STMT, VMCNT_STMT)        \
  {                                                                         \
    const u16* Abase = lsA + (ASLOT) * 8192;                                \
    bf16x8 aF[4];                                                           \
    _Pragma("unroll") for (int f = 0; f < 4; ++f)                           \
        aF[f] = *(const bf16x8*)(Abase + aro + ((AH) * 4 + f) * 512);       \
    if (RELOAD_B) {                                                         \
      const u16* Bbase = lsB + (BSLOT) * 4096;                              \
      _Pragma("unroll") for (int g = 0; g < 2; ++g)                         \
          bF[g] = *(const bf16x8*)(Bbase + bro + g * 512);                  \
    }                                                                       \
    STAGE_STMT;                                                             \
    __builtin_amdgcn_s_barrier();                                           \
    asm volatile("s_waitcnt lgkmcnt(0)" ::: "memory");                      \
    __builtin_amdgcn_s_setprio(1);                                          \
    _Pragma("unroll") for (int f = 0; f < 4; ++f)                           \
        _Pragma("unroll") for (int g = 0; g < 2; ++g)                       \
            acc[(AH) * 4 + f][g] = __builtin_amdgcn_mfma_f32_16x16x32_bf16( \
                aF[f], bF[g], acc[(AH) * 4 + f][g], 0, 0, 0);               \
    __builtin_amdgcn_s_setprio(0);                                          \
    VMCNT_STMT;                                                             \
    __builtin_amdgcn_s_barrier();                                           \
  }

  // Prologue: 7 half-stages (10 loads); vmcnt(4) = all but newest 3 stages.
  STAGE_B2(0, 0);
  STAGE_A2(0, 0);
  STAGE_B2(1, 32);
  STAGE_A2(1, 32);
  STAGE_B2(2, 64);
  STAGE_A2(2, 64);
  STAGE_B2(3, 96);
  asm volatile("s_waitcnt vmcnt(4)" ::: "memory");
  __builtin_amdgcn_s_barrier();

#pragma unroll 1
  for (int i = 0; i < 8; ++i) {  // 2 K-tiles per iteration (K=128)
    const int c1 = (2 * i + 1) * 64;
    const int c2 = ((2 * i + 2) & 15) * 64;
    const int c3 = ((2 * i + 3) & 15) * 64;
    G2_PHASE(0, 0, 0, 1, STAGE_A2(3, c1 + 32), (void)0);
    G2_PHASE(0, 0, 1, 0, STAGE_B2(0, c2), (void)0);
    G2_PHASE(1, 1, 0, 1, STAGE_A2(0, c2), (void)0);
    G2_PHASE(1, 1, 1, 0, STAGE_B2(1, c2 + 32),
             asm volatile("s_waitcnt vmcnt(4)" ::: "memory"));
    G2_PHASE(2, 2, 0, 1, STAGE_A2(1, c2 + 32), (void)0);
    G2_PHASE(2, 2, 1, 0, STAGE_B2(2, c3), (void)0);
    G2_PHASE(3, 3, 0, 1, STAGE_A2(2, c3), (void)0);
    G2_PHASE(3, 3, 1, 0, STAGE_B2(3, c3 + 32),
             asm volatile("s_waitcnt vmcnt(4)" ::: "memory"));
  }
#undef G2_PHASE
#undef STAGE_A2
#undef STAGE_B2

  asm volatile("s_waitcnt vmcnt(0)" ::: "memory");  // drain tail dummy DMAs

  // Epilogue: D col = batch (m16), D row = o (quad*4 + reg). f32x4 partials.
  float* part = g_part + (size_t)zidx * ((size_t)BATCH * OUTF);
#pragma unroll
  for (int fa = 0; fa < 8; ++fa) {
    int og = M0 + wm * 128 + fa * 16 + quad * 4;
#pragma unroll
    for (int fb = 0; fb < 2; ++fb) {
      int bg = N0 + wn * 32 + fb * 16 + m16;
      *(f32x4*)(part + (size_t)bg * OUTF + og) = acc[fa][fb];
    }
  }
}

// ------------- out += sum_z part[z] -------------
__global__ __launch_bounds__(256) void reduce_kernel(float* __restrict__ out) {
  int i = (blockIdx.x * 256 + threadIdx.x) * 4;
  float4 s = *(const float4*)(out + i);  // seed = mix @ b2s
#pragma unroll
  for (int z = 0; z < ZSPL; ++z) {
    const float4 p = *(const float4*)(g_part + (size_t)z * BATCH * OUTF + i);
    s.x += p.x; s.y += p.y; s.z += p.z; s.w += p.w;
  }
  *(float4*)(out + i) = s;
}

extern "C" void kernel_launch(void* const* d_in, const int* in_sizes, int n_in,
                              void* d_out, int out_size, void* d_ws, size_t ws_size,
                              hipStream_t stream) {
  const float* x = (const float*)d_in[0];
  const float* nw = (const float*)d_in[1];
  const float* nb = (const float*)d_in[2];
  const float* w1s = (const float*)d_in[3];
  const float* b1s = (const float*)d_in[4];
  const float* w2s = (const float*)d_in[5];
  const float* b2s = (const float*)d_in[6];
  float* out = (float*)d_out;
  (void)d_ws; (void)ws_size;

  hipLaunchKernelGGL(prep_kernel, dim3(3656), dim3(256), 0, stream,
                     x, nw, w1s, w2s, b2s);
  hipLaunchKernelGGL(mixture_kernel, dim3(256), dim3(256), 0, stream, nb, out);
  hipLaunchKernelGGL(gemm1_kernel, dim3(256), dim3(512), 0, stream, b1s);
  hipLaunchKernelGGL(gemm2_kernel, dim3(256), dim3(512), 0, stream);
  hipLaunchKernelGGL(reduce_kernel, dim3(2048), dim3(256), 0, stream, out);
}

// Round 12
// 187.883 us; speedup vs baseline: 1.0231x; 1.0231x over previous
//
#include <hip/hip_runtime.h>
#include <hip/hip_bf16.h>

typedef unsigned short u16;
typedef __attribute__((ext_vector_type(8))) short bf16x8;
typedef __attribute__((ext_vector_type(4))) float f32x4;
typedef __attribute__((ext_vector_type(16))) float f32x16;
typedef __attribute__((ext_vector_type(4))) unsigned short u16x4;
typedef __attribute__((ext_vector_type(8))) unsigned short u16x8;

#define BATCH 4096
#define INF   1024
#define NH    4096   // 64 leaves * 64 hidden
#define OUTF  512
#define NLEAF 64
#define FDEPTH 6
#define ZSPL  4      // GEMM2 split-K ways

// Scratch as device globals (fully rewritten every call; no ws_size dependency).
__device__ __align__(16) u16  g_Xb[(size_t)BATCH * INF];     // x, bf16 (b,k)
__device__ __align__(16) u16  g_W1t[(size_t)NH * INF];       // W1 transposed: (n,k)
__device__ __align__(16) u16  g_W2t[(size_t)OUTF * NH];      // W2 transposed: (o,k)
__device__ __align__(16) u16  g_NWh[(size_t)64 * INF];       // node weights bf16 (row63=0)
__device__ __align__(16) u16  g_B2t[(size_t)OUTF * 64];      // b2s transposed (o,l) bf16
__device__ __align__(16) u16  g_Hb[(size_t)BATCH * NH];      // H' = mix*relu(h), bf16
__device__ __align__(16) float g_mix[(size_t)BATCH * NLEAF];
__device__ __align__(16) float g_part[(size_t)ZSPL * BATCH * OUTF];  // GEMM2 partials

__device__ inline u16 f2b(float f) {
  __hip_bfloat16 h = __float2bfloat16(f);
  return *reinterpret_cast<u16*>(&h);
}

// Direct global->LDS DMA, 16 B per lane; LDS dest = wave-uniform base + lane*16.
__device__ inline void async16(const u16* g, u16* l) {
  __builtin_amdgcn_global_load_lds((const __attribute__((address_space(1))) void*)g,
                                   (__attribute__((address_space(3))) void*)l, 16, 0, 0);
}

// ------------- merged prep: casts + transposes, section-decoded -------------
__global__ __launch_bounds__(256) void prep_kernel(
    const float* __restrict__ x, const float* __restrict__ nw,
    const float* __restrict__ w1s, const float* __restrict__ w2s,
    const float* __restrict__ b2s) {
  __shared__ float tile[64 * 65];
  const int b = blockIdx.x;
  const int t = threadIdx.x;

  if (b < 2048) {  // ---- cast x ----
    int i = (b * 256 + t) * 8;
    float4 v0 = *(const float4*)(x + i);
    float4 v1 = *(const float4*)(x + i + 4);
    u16x8 h;
    h[0] = f2b(v0.x); h[1] = f2b(v0.y); h[2] = f2b(v0.z); h[3] = f2b(v0.w);
    h[4] = f2b(v1.x); h[5] = f2b(v1.y); h[6] = f2b(v1.z); h[7] = f2b(v1.w);
    *(u16x8*)(g_Xb + i) = h;
    return;
  }
  if (b < 2112) {  // ---- cast nw ----
    int idx = ((b - 2048) * 256 + t) * 4;
    int n = idx >> 10;
    float4 v = make_float4(0.f, 0.f, 0.f, 0.f);
    if (n < 63) v = *(const float4*)(nw + idx);
    u16x4 h;
    h[0] = f2b(v.x); h[1] = f2b(v.y); h[2] = f2b(v.z); h[3] = f2b(v.w);
    *(u16x4*)(g_NWh + idx) = h;
    return;
  }

  // ---- transpose-cast sections: dst[c][r] = src[r][c] per 64x64 tile ----
  const float* sb;
  u16* db;
  int R, C, r0, c0;
  if (b < 3136) {
    int idx = b - 2112;
    int z = idx >> 4;
    R = 1024; C = 64;
    r0 = (idx & 15) * 64; c0 = 0;
    sb = w1s + (size_t)z * R * C;
    db = g_W1t + (size_t)z * R * C;
  } else if (b < 3648) {
    int idx = b - 3136;
    R = 4096; C = 512;
    r0 = (idx >> 3) * 64; c0 = (idx & 7) * 64;
    sb = w2s;
    db = g_W2t;
  } else {
    int idx = b - 3648;
    R = 64; C = 512;
    r0 = 0; c0 = idx * 64;
    sb = b2s;
    db = g_B2t;
  }
  int cc4 = (t & 15) * 4;
#pragma unroll
  for (int it = 0; it < 4; ++it) {
    int rr = (t >> 4) + it * 16;
    float4 v = *(const float4*)(sb + (size_t)(r0 + rr) * C + c0 + cc4);
    tile[rr * 65 + cc4 + 0] = v.x;
    tile[rr * 65 + cc4 + 1] = v.y;
    tile[rr * 65 + cc4 + 2] = v.z;
    tile[rr * 65 + cc4 + 3] = v.w;
  }
  __syncthreads();
  int cc = t >> 2, rch = (t & 3) * 16;
  u16x8 o0, o1;
#pragma unroll
  for (int j = 0; j < 8; ++j) o0[j] = f2b(tile[(rch + j) * 65 + cc]);
#pragma unroll
  for (int j = 0; j < 8; ++j) o1[j] = f2b(tile[(rch + 8 + j) * 65 + cc]);
  u16* p = db + (size_t)(c0 + cc) * R + r0 + rch;
  *(u16x8*)p = o0;
  *(u16x8*)(p + 8) = o1;
}

// ------------- fused mixture: MFMA logits + sigmoid + tree product -> g_mix
//               + MFMA seed out = mix@b2 -------------
__global__ __launch_bounds__(256) void mixture_kernel(
    const float* __restrict__ nb, float* __restrict__ out) {
  __shared__ __align__(16) unsigned char lds[57344];
  const int t = threadIdx.x;
  const int wv = t >> 6, ln = t & 63;
  const int quad = ln >> 4, m16 = ln & 15;
  const int r0 = blockIdx.x * 16;

  u16* stW = (u16*)(lds + wv * 10240);
  u16* stX = (u16*)(lds + wv * 10240 + 8192);
  float* lred = (float*)lds;
  float* ssig = (float*)(lds + 16384);
  u16* smixb = (u16*)(lds + 20480);
  u16* b2l = (u16*)(lds + 24576);

  f32x4 acc[4] = {};
#pragma unroll 1
  for (int it = 0; it < 4; ++it) {
    int kc = wv * 256 + it * 64;
#pragma unroll
    for (int j = 0; j < 8; ++j) {
      int id = j * 64 + ln;
      int row = id >> 3, c8 = (id & 7) ^ (row & 7);
      async16(g_NWh + (size_t)row * INF + kc + c8 * 8, stW + j * 512);
    }
#pragma unroll
    for (int j = 0; j < 2; ++j) {
      int id = j * 64 + ln;
      int row = id >> 3, c8 = (id & 7) ^ (row & 7);
      async16(g_Xb + (size_t)(r0 + row) * INF + kc + c8 * 8, stX + j * 512);
    }
    __syncthreads();
#pragma unroll
    for (int ks = 0; ks < 2; ++ks) {
      bf16x8 bF = *(const bf16x8*)(stX + m16 * 64 + ((ks * 4 + quad) ^ (m16 & 7)) * 8);
#pragma unroll
      for (int tw = 0; tw < 4; ++tw) {
        int row = tw * 16 + m16;
        bf16x8 aF = *(const bf16x8*)(stW + row * 64 + ((ks * 4 + quad) ^ (row & 7)) * 8);
        acc[tw] = __builtin_amdgcn_mfma_f32_16x16x32_bf16(aF, bF, acc[tw], 0, 0, 0);
      }
    }
    __syncthreads();
  }
#pragma unroll
  for (int tw = 0; tw < 4; ++tw)
#pragma unroll
    for (int r = 0; r < 4; ++r)
      lred[((size_t)wv * 64 + tw * 16 + quad * 4 + r) * 16 + m16] = acc[tw][r];
  __syncthreads();

#pragma unroll
  for (int j = 0; j < 8; ++j) {
    int id = (wv * 8 + j) * 64 + ln;
    int row = id >> 3, c8 = (id & 7) ^ (row & 7);
    async16(g_B2t + (size_t)row * 64 + c8 * 8, b2l + (wv * 8 + j) * 512);
  }

  {
    int n = t & 63, rg = t >> 6;
#pragma unroll
    for (int rr = 0; rr < 4; ++rr) {
      int row = rg * 4 + rr;
      float s = lred[(0 * 64 + n) * 16 + row] + lred[(1 * 64 + n) * 16 + row] +
                lred[(2 * 64 + n) * 16 + row] + lred[(3 * 64 + n) * 16 + row];
      if (n < 63) s += nb[n];
      ssig[row * 64 + n] = 1.f / (1.f + __expf(-s));
    }
  }
  __syncthreads();
  {
    int leaf = t & 63, rg = t >> 6;
#pragma unroll
    for (int rr = 0; rr < 4; ++rr) {
      int row = rg * 4 + rr;
      float p = 1.f;
#pragma unroll
      for (int d = 0; d < FDEPTH; ++d) {
        int node = (1 << d) - 1 + (leaf >> (FDEPTH - d));
        int bit = (leaf >> (FDEPTH - 1 - d)) & 1;
        float s = ssig[row * 64 + node];
        p *= bit ? s : (1.f - s);
      }
      g_mix[(size_t)(r0 + row) * 64 + leaf] = p;
      smixb[row * 64 + ((leaf >> 3) ^ (row & 7)) * 8 + (leaf & 7)] = f2b(p);
    }
  }
  __syncthreads();

  bf16x8 mixF[2];
#pragma unroll
  for (int ks = 0; ks < 2; ++ks)
    mixF[ks] = *(const bf16x8*)(smixb + m16 * 64 + ((ks * 4 + quad) ^ (m16 & 7)) * 8);
#pragma unroll 1
  for (int s = 0; s < 2; ++s) {
    f32x4 sacc[4] = {};
#pragma unroll
    for (int tile = 0; tile < 4; ++tile) {
#pragma unroll
      for (int ks = 0; ks < 2; ++ks) {
        int lrow = wv * 64 + tile * 16 + m16;
        bf16x8 aF = *(const bf16x8*)(b2l + lrow * 64 + ((ks * 4 + quad) ^ (lrow & 7)) * 8);
        sacc[tile] = __builtin_amdgcn_mfma_f32_16x16x32_bf16(aF, mixF[ks], sacc[tile], 0, 0, 0);
      }
    }
#pragma unroll
    for (int tile = 0; tile < 4; ++tile) {
      int o = s * 256 + wv * 64 + tile * 16 + quad * 4;
      *(f32x4*)(out + (size_t)(r0 + m16) * OUTF + o) = sacc[tile];
    }
    if (s == 0) {
      __syncthreads();
#pragma unroll
      for (int j = 0; j < 8; ++j) {
        int id = (wv * 8 + j) * 64 + ln;
        int row = id >> 3, c8 = (id & 7) ^ (row & 7);
        async16(g_B2t + (size_t)(256 + row) * 64 + c8 * 8, b2l + (wv * 8 + j) * 512);
      }
      __syncthreads();
    }
  }
}

// ------------- GEMM1: H'(b,n) = mix * relu(Xb @ W1t^T + b1) -------------
// 8-phase 256x256 pipelined schedule, frozen at R5 form (49.5 us, conflicts=0,
// FETCH 30 MB): phase {barrier; lgkmcnt(0); setprio(1); 16 MFMA; setprio(0);
// [vmcnt(6) @P4/P8]; barrier}; both-sides granule swizzle keyed on row bits
// [2:1]; XCD-compact tile map. R11's merged-phase variant (32x32) was
// neutral-to-worse (54 vs 50 us) — phase cost scales with the serialized
// LDS read+DMA stream, not barrier count; reverted to this form.
__global__ __launch_bounds__(512, 2) void gemm1_kernel(const float* __restrict__ b1) {
  __shared__ __align__(16) u16 s_lds[65536];  // 128 KiB
  u16* lsA = s_lds;            // 4 slots x 8192 u16 (256 rows x 32)
  u16* lsB = s_lds + 32768;

  const int t = threadIdx.x;
  const int wv = t >> 6, ln = t & 63;
  const int quad = ln >> 4, m16 = ln & 15;
  const int wm = wv >> 2, wn = wv & 3;      // 2 x 4 wave grid
  const int xcd = blockIdx.x & 7, slot = blockIdx.x >> 3;
  const int M0 = ((xcd >> 1) * 4 + (slot & 3)) * 256;   // weight rows (n)
  const int N0 = ((xcd & 1) * 8 + (slot >> 2)) * 256;   // batch rows (b)

  const int rhalf = ln >> 2;
  const int qg = (ln & 3) ^ ((ln >> 3) & 3);
  const u16* pA = g_W1t + (size_t)(M0 + wv * 32 + rhalf) * 1024 + qg * 8;
  const u16* pB = g_Xb + (size_t)(N0 + wv * 32 + rhalf) * 1024 + qg * 8;
  const int dst0 = wv * 1024;  // u16 offset of this wave's 2KB chunk in a slot

  // ds_read: row*32 + (quad ^ ((row>>1)&3))*8 ; (row>>1)&3 == (m16>>1)&3
  const int qx = (quad ^ ((m16 >> 1) & 3)) * 8;
  const int aro = (wm * 128 + m16) * 32 + qx;
  const int bro = (wn * 64 + m16) * 32 + qx;

  f32x4 acc[8][4] = {};
  bf16x8 bF[4];

#define STAGE_A(SLOT, TCOL)                                \
  do {                                                     \
    const u16* gs = pA + (TCOL);                           \
    u16* dd = lsA + (SLOT) * 8192 + dst0;                  \
    async16(gs, dd);                                       \
    async16(gs + 16 * 1024, dd + 512);                     \
  } while (0)
#define STAGE_B(SLOT, TCOL)                                \
  do {                                                     \
    const u16* gs = pB + (TCOL);                           \
    u16* dd = lsB + (SLOT) * 8192 + dst0;                  \
    async16(gs, dd);                                       \
    async16(gs + 16 * 1024, dd + 512);                     \
  } while (0)

#define G1_PHASE(ASLOT, BSLOT, AH, RELOAD_B, STAGE_STMT, VMCNT_STMT)        \
  {                                                                         \
    const u16* Abase = lsA + (ASLOT) * 8192;                                \
    bf16x8 aF[4];                                                           \
    _Pragma("unroll") for (int f = 0; f < 4; ++f)                           \
        aF[f] = *(const bf16x8*)(Abase + aro + ((AH) * 4 + f) * 512);       \
    if (RELOAD_B) {                                                         \
      const u16* Bbase = lsB + (BSLOT) * 8192;                              \
      _Pragma("unroll") for (int f = 0; f < 4; ++f)                         \
          bF[f] = *(const bf16x8*)(Bbase + bro + f * 512);                  \
    }                                                                       \
    STAGE_STMT;                                                             \
    __builtin_amdgcn_s_barrier();                                           \
    asm volatile("s_waitcnt lgkmcnt(0)" ::: "memory");                      \
    __builtin_amdgcn_s_setprio(1);                                          \
    _Pragma("unroll") for (int f = 0; f < 4; ++f)                           \
        _Pragma("unroll") for (int g = 0; g < 4; ++g)                       \
            acc[(AH) * 4 + f][g] = __builtin_amdgcn_mfma_f32_16x16x32_bf16( \
                aF[f], bF[g], acc[(AH) * 4 + f][g], 0, 0, 0);               \
    __builtin_amdgcn_s_setprio(0);                                          \
    VMCNT_STMT;                                                             \
    __builtin_amdgcn_s_barrier();                                           \
  }

  // Prologue: 7 halves (14 loads); vmcnt(6) -> tile0's 4 halves landed.
  STAGE_B(0, 0);    // B(0,0)
  STAGE_A(0, 0);    // A(0,0)
  STAGE_B(1, 32);   // B(0,1)
  STAGE_A(1, 32);   // A(0,1)
  STAGE_B(2, 64);   // B(1,0)
  STAGE_A(2, 64);   // A(1,0)
  STAGE_B(3, 96);   // B(1,1)
  asm volatile("s_waitcnt vmcnt(6)" ::: "memory");
  __builtin_amdgcn_s_barrier();

#pragma unroll 1
  for (int i = 0; i < 8; ++i) {  // 2 K-tiles (t0=2i, t1=2i+1) per iteration
    const int c1 = (2 * i + 1) * 64;
    const int c2 = ((2 * i + 2) & 15) * 64;
    const int c3 = ((2 * i + 3) & 15) * 64;
    G1_PHASE(0, 0, 0, 1, STAGE_A(3, c1 + 32), (void)0);
    G1_PHASE(0, 0, 1, 0, STAGE_B(0, c2), (void)0);
    G1_PHASE(1, 1, 0, 1, STAGE_A(0, c2), (void)0);
    G1_PHASE(1, 1, 1, 0, STAGE_B(1, c2 + 32),
             asm volatile("s_waitcnt vmcnt(6)" ::: "memory"));
    G1_PHASE(2, 2, 0, 1, STAGE_A(1, c2 + 32), (void)0);
    G1_PHASE(2, 2, 1, 0, STAGE_B(2, c3), (void)0);
    G1_PHASE(3, 3, 0, 1, STAGE_A(2, c3), (void)0);
    G1_PHASE(3, 3, 1, 0, STAGE_B(3, c3 + 32),
             asm volatile("s_waitcnt vmcnt(6)" ::: "memory"));
  }
#undef G1_PHASE
#undef STAGE_A
#undef STAGE_B

  asm volatile("s_waitcnt vmcnt(0)" ::: "memory");  // drain tail dummy DMAs

  // Epilogue: D col = batch (m16), D row = n (quad*4 + reg) — verified map.
  const int lb = (M0 >> 6) + wm * 2;  // leaf for fa<4; lb+1 for fa>=4
  float2 mx[4];
#pragma unroll
  for (int fb = 0; fb < 4; ++fb) {
    int bb = N0 + wn * 64 + fb * 16 + m16;
    mx[fb] = *(const float2*)(g_mix + (size_t)bb * 64 + lb);
  }
#pragma unroll
  for (int fa = 0; fa < 8; ++fa) {
    int n0 = M0 + wm * 128 + fa * 16 + quad * 4;
    float4 b1v = *(const float4*)(b1 + n0);
#pragma unroll
    for (int fb = 0; fb < 4; ++fb) {
      int bb = N0 + wn * 64 + fb * 16 + m16;
      float mixv = (fa < 4) ? mx[fb].x : mx[fb].y;
      u16x4 pk;
      pk[0] = f2b(fmaxf(acc[fa][fb][0] + b1v.x, 0.f) * mixv);
      pk[1] = f2b(fmaxf(acc[fa][fb][1] + b1v.y, 0.f) * mixv);
      pk[2] = f2b(fmaxf(acc[fa][fb][2] + b1v.z, 0.f) * mixv);
      pk[3] = f2b(fmaxf(acc[fa][fb][3] + b1v.w, 0.f) * mixv);
      *(u16x4*)(g_Hb + (size_t)bb * NH + n0) = pk;
    }
  }
}

// ------------- GEMM2: part[z](b,o) = Hb @ W2t^T (split-K partials) -------------
// R7 form (best measured total, 188.5 us). 8-phase port with 256 o x 128 b
// tile, ZSPL=4 -> 256 blocks x 512 thr, K=1024/block = 8 K-tiles. LDS: A
// 4x16KB + B 4x8KB = 96KB. vmcnt(4) = newest 3 stages (B1+A2+B1) in flight.
__global__ __launch_bounds__(512, 2) void gemm2_kernel() {
  __shared__ __align__(16) u16 s_lds[49152];  // 96 KiB
  u16* lsA = s_lds;            // W2t: 4 slots x 8192 u16 (256 rows x 32)
  u16* lsB = s_lds + 32768;    // Hb:  4 slots x 4096 u16 (128 rows x 32)

  const int t = threadIdx.x;
  const int wv = t >> 6, ln = t & 63;
  const int quad = ln >> 4, m16 = ln & 15;
  const int wm = wv >> 2, wn = wv & 3;      // wm: o-half (128), wn: b-quarter (32)
  const int xcd = blockIdx.x & 7, slot = blockIdx.x >> 3;   // 32 slots/XCD
  const int btile = xcd * 4 + (slot >> 3);  // 0..31 (128 batch rows each)
  const int rem = slot & 7;
  const int mtile = rem & 1, zidx = rem >> 1;
  const int N0 = btile * 128;               // batch base
  const int M0 = mtile * 256;               // o base
  const int kbeg = zidx * 1024;

  const int rhalf = ln >> 2;
  const int qg = (ln & 3) ^ ((ln >> 3) & 3);
  const u16* pA = g_W2t + (size_t)(M0 + wv * 32 + rhalf) * 4096 + kbeg + qg * 8;
  const u16* pB = g_Hb + (size_t)(N0 + wv * 16 + rhalf) * 4096 + kbeg + qg * 8;
  const int dstA = wv * 1024;  // wave's 2KB chunk in a 16KB A-slot
  const int dstB = wv * 512;   // wave's 1KB chunk in an 8KB B-slot

  const int qx = (quad ^ ((m16 >> 1) & 3)) * 8;
  const int aro = (wm * 128 + m16) * 32 + qx;
  const int bro = (wn * 32 + m16) * 32 + qx;

  f32x4 acc[8][2] = {};
  bf16x8 bF[2];

#define STAGE_A2(SLOT, TCOL)                               \
  do {                                                     \
    const u16* gs = pA + (TCOL);                           \
    u16* dd = lsA + (SLOT) * 8192 + dstA;                  \
    async16(gs, dd);                                       \
    async16(gs + 16 * 4096, dd + 512);                     \
  } while (0)
#define STAGE_B2(SLOT, TCOL)                               \
  do {                                                     \
    const u16* gs = pB + (TCOL);                           \
    u16* dd = lsB + (SLOT) * 4096 + dstB;                  \
    async16(gs, dd);                                       \
  } while (0)

#define G2_PHASE(ASLOT, BSLOT, AH, RELOAD_B, STAGE_STMT, VMCNT_STMT)        \
  {                                                                         \
    const u16* Abase = lsA + (ASLOT) * 8192;                                \
    bf16x8 aF[4];                                                           \
    _Pragma("unroll") for (int f = 0; f < 4; ++f)                           \
        aF[f] = *(const bf16x8*)(Abase + aro + ((AH) * 4 + f) * 512);       \
    if (RELOAD_B) {                                                         \
      const u16* Bbase = lsB + (BSLOT) * 4096;                              \
      _Pragma("unroll") for (int g = 0; g < 2; ++g)                         \
          bF[g] = *(const bf16x8*)(Bbase + bro + g * 512);                  \
    }                                                                       \
    STAGE_STMT;                                                             \
    __builtin_amdgcn_s_barrier();                                           \
    asm volatile("s_waitcnt lgkmcnt(0)" ::: "memory");                      \
    __builtin_amdgcn_s_setprio(1);                                          \
    _Pragma("unroll") for (int f = 0; f < 4; ++f)                           \
        _Pragma("unroll") for (int g = 0; g < 2; ++g)                       \
            acc[(AH) * 4 + f][g] = __builtin_amdgcn_mfma_f32_16x16x32_bf16( \
                aF[f], bF[g], acc[(AH) * 4 + f][g], 0, 0, 0);               \
    __builtin_amdgcn_s_setprio(0);                                          \
    VMCNT_STMT;                                                             \
    __builtin_amdgcn_s_barrier();                                           \
  }

  // Prologue: 7 half-stages (10 loads); vmcnt(4) = all but newest 3 stages.
  STAGE_B2(0, 0);
  STAGE_A2(0, 0);
  STAGE_B2(1, 32);
  STAGE_A2(1, 32);
  STAGE_B2(2, 64);
  STAGE_A2(2, 64);
  STAGE_B2(3, 96);
  asm volatile("s_waitcnt vmcnt(4)" ::: "memory");
  __builtin_amdgcn_s_barrier();

#pragma unroll 1
  for (int i = 0; i < 8; ++i) {  // 2 K-tiles per iteration (K=128)
    const int c1 = (2 * i + 1) * 64;
    const int c2 = ((2 * i + 2) & 15) * 64;
    const int c3 = ((2 * i + 3) & 15) * 64;
    G2_PHASE(0, 0, 0, 1, STAGE_A2(3, c1 + 32), (void)0);
    G2_PHASE(0, 0, 1, 0, STAGE_B2(0, c2), (void)0);
    G2_PHASE(1, 1, 0, 1, STAGE_A2(0, c2), (void)0);
    G2_PHASE(1, 1, 1, 0, STAGE_B2(1, c2 + 32),
             asm volatile("s_waitcnt vmcnt(4)" ::: "memory"));
    G2_PHASE(2, 2, 0, 1, STAGE_A2(1, c2 + 32), (void)0);
    G2_PHASE(2, 2, 1, 0, STAGE_B2(2, c3), (void)0);
    G2_PHASE(3, 3, 0, 1, STAGE_A2(2, c3), (void)0);
    G2_PHASE(3, 3, 1, 0, STAGE_B2(3, c3 + 32),
             asm volatile("s_waitcnt vmcnt(4)" ::: "memory"));
  }
#undef G2_PHASE
#undef STAGE_A2
#undef STAGE_B2

  asm volatile("s_waitcnt vmcnt(0)" ::: "memory");  // drain tail dummy DMAs

  // Epilogue: D col = batch (m16), D row = o (quad*4 + reg). f32x4 partials.
  float* part = g_part + (size_t)zidx * ((size_t)BATCH * OUTF);
#pragma unroll
  for (int fa = 0; fa < 8; ++fa) {
    int og = M0 + wm * 128 + fa * 16 + quad * 4;
#pragma unroll
    for (int fb = 0; fb < 2; ++fb) {
      int bg = N0 + wn * 32 + fb * 16 + m16;
      *(f32x4*)(part + (size_t)bg * OUTF + og) = acc[fa][fb];
    }
  }
}

// ------------- out += sum_z part[z] -------------
__global__ __launch_bounds__(256) void reduce_kernel(float* __restrict__ out) {
  int i = (blockIdx.x * 256 + threadIdx.x) * 4;
  float4 s = *(const float4*)(out + i);  // seed = mix @ b2s
#pragma unroll
  for (int z = 0; z < ZSPL; ++z) {
    const float4 p = *(const float4*)(g_part + (size_t)z * BATCH * OUTF + i);
    s.x += p.x; s.y += p.y; s.z += p.z; s.w += p.w;
  }
  *(float4*)(out + i) = s;
}

extern "C" void kernel_launch(void* const* d_in, const int* in_sizes, int n_in,
                              void* d_out, int out_size, void* d_ws, size_t ws_size,
                              hipStream_t stream) {
  const float* x = (const float*)d_in[0];
  const float* nw = (const float*)d_in[1];
  const float* nb = (const float*)d_in[2];
  const float* w1s = (const float*)d_in[3];
  const float* b1s = (const float*)d_in[4];
  const float* w2s = (const float*)d_in[5];
  const float* b2s = (const float*)d_in[6];
  float* out = (float*)d_out;
  (void)d_ws; (void)ws_size;

  hipLaunchKernelGGL(prep_kernel, dim3(3656), dim3(256), 0, stream,
                     x, nw, w1s, w2s, b2s);
  hipLaunchKernelGGL(mixture_kernel, dim3(256), dim3(256), 0, stream, nb, out);
  hipLaunchKernelGGL(gemm1_kernel, dim3(256), dim3(512), 0, stream, b1s);
  hipLaunchKernelGGL(gemm2_kernel, dim3(256), dim3(512), 0, stream);
  hipLaunchKernelGGL(reduce_kernel, dim3(2048), dim3(256), 0, stream, out);
}